// Round 7
// baseline (158.272 us; speedup 1.0000x reference)
//
#include <hip/hip_runtime.h>
#include <hip/hip_bf16.h>

#define NSTEP 50
#define S51 51
#define HID 128
#define MT 64                  // rows per tile (64 proven best: 4 blocks/CU)
#define BPB 16                 // batch elems per block (block owns them -> no global atomics)
#define RPB (BPB * S51)        // 816 valid rows per block
#define NTILE 13               // ceil(816/64)
#define GRID (16384 / BPB)     // 1024 blocks
#define BLOCK 256              // 4 waves; wave mi owns hidden slice [mi*32, mi*32+32)

typedef __attribute__((ext_vector_type(4))) float floatx4;
typedef __attribute__((ext_vector_type(16))) float floatx16;
typedef __attribute__((ext_vector_type(8))) __bf16 bf16x8;

// 4 x f32 -> 4 packed fp8 e4m3 bytes (v_cvt_pk_fp8_f32, gfx950 OCP e4m3fn)
__device__ __forceinline__ unsigned pk4_fp8(float v0, float v1, float v2, float v3) {
    unsigned r = (unsigned)__builtin_amdgcn_cvt_pk_fp8_f32(v0, v1, 0, false);   // bytes 0,1
    r = (unsigned)__builtin_amdgcn_cvt_pk_fp8_f32(v2, v3, (int)r, true);        // bytes 2,3
    return r;
}

// Swizzled fp8 A2 layout (64x128 B): phys_chunk = chunk ^ (row&15). XOR-base:
//   rb = l31*128 + ((l31&15)<<3)  (disjoint bits)
//   reads:  addr = (rb ^ (hi<<3)) ^ (kc<<4)  [+4096 for row l31+32]
//   writes: addr = ((rb+4*hi) ^ (mi<<5)) ^ (g<<3)  [+4096 for row l31+32]

// Register-only C-operand build (address-taken aggregates spill — R7 lesson)
__device__ __forceinline__ floatx16 ld_bias16(const float* bs, int base) {
    const floatx4 t0 = *(const floatx4*)(&bs[base]);
    const floatx4 t1 = *(const floatx4*)(&bs[base + 8]);
    const floatx4 t2 = *(const floatx4*)(&bs[base + 16]);
    const floatx4 t3 = *(const floatx4*)(&bs[base + 24]);
    floatx16 v = {t0[0], t0[1], t0[2], t0[3], t1[0], t1[1], t1[2], t1[3],
                  t2[0], t2[1], t2[2], t2[3], t3[0], t3[1], t3[2], t3[3]};
    return v;
}

// fp8 pack of one 32-row D fragment -> swizzled A2 (canonical hidden layout)
__device__ __forceinline__ void pack_row(unsigned char* dst, floatx16 a, int wb) {
#pragma unroll
    for (int g = 0; g < 4; ++g) {
        unsigned p = pk4_fp8(fmaxf(a[4 * g + 0], 0.0f), fmaxf(a[4 * g + 1], 0.0f),
                             fmaxf(a[4 * g + 2], 0.0f), fmaxf(a[4 * g + 3], 0.0f));
        *(unsigned*)(&dst[wb ^ (g << 3)]) = p;
    }
}

// R21: A1 LDS buffer ELIMINATED via K-permutation. R20 post-mortem: barrier
// stall is NOT fixed-cost — it's latency hidden by cross-block TLP; 2 blocks/CU
// killed that (occupancy >= 4 blocks/CU is load-bearing). R18 budget re-audit:
// DS ~6k cyc/CU/phase (52 instr/wave) is CO-BOTTLENECK with MFMA 4.4k; biggest
// DS item = L1->LDS->L2 round trip. Key identity: L2's K-sum order is free, so
// permute hidden s.t. L1's D-frag IS L2's B-frag byte-for-byte:
//   D reg r (lane l31,hi) holds hidden 4hi+(r&3)+8(r>>2) of slice q, col=l31;
//   B-frag(kc=2q+j) byte e needs hidden q*32+j*16+4hi+(e&3)+8(e>>2)  =>  r=8j+e.
// w2f gathered with the SAME permutation; w3f/A2/L3 stay canonical. Each wave
// runs L1 in-register for all 4 slices (8 bf16 MFMA vs 2): -16 ds_read -8
// ds_write per wave-phase (~45% DS), -16KB LDS, L1->barrier->L2 dep gone.
// LEDGER: R16 runtime-parity fuse (spills), R19 ci-hoist@4waves (spills),
// R20 MT=128 (occupancy >> barriers), R9 LDS, R13/R14 packed-f32.
// Spill guard: FETCH <= ~1MB, WRITE ~64KB.
template<int PA, bool CONS, bool L2P, bool L3P>
__device__ __forceinline__ void phase(int s,
        unsigned char (&A2)[2][MT * HID], float (&posum)[2][4][MT],
        const float* b2s, const float* b3s, const float* w4s,
        const float* fs, const float* ts,
        float& accq, const long (&w2f)[8], const long (&w3f)[8],
        const bf16x8 (&aw)[4], float xv, __bf16 hb, float hm, float b4v,
        int rbh, int wbm, int tid, int l31, int hi, int mi) {
    constexpr int PB = PA ^ 1;
    // ---- consume tile s-2 partials (posum[PA], written phase s-1; in-loop
    //      tiles 0..11 fully valid: lr < 768 < RPB) ----
    if (CONS) {
        if (tid < MT) {
            int lr = (s - 2) * MT + tid;
            float u = posum[PA][0][tid] + posum[PA][1][tid] + posum[PA][2][tid]
                    + posum[PA][3][tid] + b4v;
            float dz = u > 0.0f ? u + 1.0f : __expf(u);  // elu(u)+1
            accq += dz * fs[lr >> 4];                    // ss = lr>>4
        }
    }
    // ---- L3-MFMA on tile s-1 (read A2[PB]) + fused L4 -> posum[PB] ----
    if (L3P) {
        const floatx16 ci = ld_bias16(b3s, mi * 32 + 4 * hi);
        long g0 = *(const long*)(&A2[PB][rbh]);
        long g1 = *(const long*)(&A2[PB][rbh + 4096]);
        floatx16 c0 = __builtin_amdgcn_mfma_f32_32x32x16_fp8_fp8(w3f[0], g0, ci, 0, 0, 0);
        floatx16 c1 = __builtin_amdgcn_mfma_f32_32x32x16_fp8_fp8(w3f[0], g1, ci, 0, 0, 0);
#pragma unroll
        for (int kc = 1; kc < 8; ++kc) {
            g0 = *(const long*)(&A2[PB][rbh ^ (kc << 4)]);
            g1 = *(const long*)(&A2[PB][(rbh ^ (kc << 4)) + 4096]);
            c0 = __builtin_amdgcn_mfma_f32_32x32x16_fp8_fp8(w3f[kc], g0, c0, 0, 0, 0);
            c1 = __builtin_amdgcn_mfma_f32_32x32x16_fp8_fp8(w3f[kc], g1, c1, 0, 0, 0);
        }
        float p0 = 0.0f, p1 = 0.0f;
#pragma unroll
        for (int g = 0; g < 4; ++g) {
            const floatx4 w4v = *(const floatx4*)(&w4s[mi * 32 + 8 * g + 4 * hi]);
#pragma unroll
            for (int rr = 0; rr < 4; ++rr) {
                p0 = fmaf(fmaxf(c0[4 * g + rr], 0.0f), w4v[rr], p0);
                p1 = fmaf(fmaxf(c1[4 * g + rr], 0.0f), w4v[rr], p1);
            }
        }
        p0 += __shfl_xor(p0, 32);
        p1 += __shfl_xor(p1, 32);
        if (hi == 0) {
            posum[PB][mi][l31] = p0;
            posum[PB][mi][l31 + 32] = p1;
        }
    }
    // ---- L1 in-register (4 slices x this rowgroup) feeding L2 directly,
    //      then pack -> A2[PA]. Two sequential rowgroups bound reg pressure. ----
    if (L2P) {
        const floatx16 ci = ld_bias16(b2s, mi * 32 + 4 * hi);
        const int s1 = 4 * s + (l31 >> 4);    // ss for row l31; rg1 is +2
        const floatx16 zz = {};
#pragma unroll
        for (int rg = 0; rg < 2; ++rg) {
            bf16x8 bx = {};
            bx[0] = (__bf16)(xv * ts[s1 + 2 * rg] * hm);
            bx[1] = hb;  bx[2] = (__bf16)hm;
            long bf[8];
#pragma unroll
            for (int q = 0; q < 4; ++q) {
                floatx16 d = __builtin_amdgcn_mfma_f32_32x32x16_bf16(aw[q], bx, zz, 0, 0, 0);
                unsigned u0 = pk4_fp8(fmaxf(d[0], 0.0f), fmaxf(d[1], 0.0f),
                                      fmaxf(d[2], 0.0f), fmaxf(d[3], 0.0f));
                unsigned u1 = pk4_fp8(fmaxf(d[4], 0.0f), fmaxf(d[5], 0.0f),
                                      fmaxf(d[6], 0.0f), fmaxf(d[7], 0.0f));
                unsigned u2 = pk4_fp8(fmaxf(d[8], 0.0f), fmaxf(d[9], 0.0f),
                                      fmaxf(d[10], 0.0f), fmaxf(d[11], 0.0f));
                unsigned u3 = pk4_fp8(fmaxf(d[12], 0.0f), fmaxf(d[13], 0.0f),
                                      fmaxf(d[14], 0.0f), fmaxf(d[15], 0.0f));
                bf[2 * q]     = (long)(((unsigned long long)u1 << 32) | u0);
                bf[2 * q + 1] = (long)(((unsigned long long)u3 << 32) | u2);
            }
            floatx16 a = __builtin_amdgcn_mfma_f32_32x32x16_fp8_fp8(w2f[0], bf[0], ci, 0, 0, 0);
#pragma unroll
            for (int kc = 1; kc < 8; ++kc)
                a = __builtin_amdgcn_mfma_f32_32x32x16_fp8_fp8(w2f[kc], bf[kc], a, 0, 0, 0);
            pack_row(&A2[PA][4096 * rg], a, wbm);
        }
    }
    __syncthreads();
}

__launch_bounds__(BLOCK, 4)
__global__ void monotonic_fused(const float* __restrict__ x, const float* __restrict__ h,
                                const float* __restrict__ w1, const float* __restrict__ b1,
                                const float* __restrict__ w2, const float* __restrict__ b2,
                                const float* __restrict__ w3, const float* __restrict__ b3,
                                const float* __restrict__ w4, const float* __restrict__ b4,
                                float* __restrict__ out) {
    __shared__ __align__(16) unsigned char A2[2][MT * HID];  // a2 fp8, 2 x 8 KB (A1 deleted)
    __shared__ float b2s[HID], b3s[HID], w4s[HID];
    __shared__ float fs[S51], ts[56];                        // ts[51..55]=0 pad
    __shared__ float xs[BPB], hs[BPB];
    __shared__ float posum[2][4][MT];                        // parity x mi x row

    const int tid = threadIdx.x;
    const int lane = tid & 63;
    const int mi = tid >> 6;      // wave 0..3 = hidden 32-slice (L2/L3 output)
    const int l31 = lane & 31;
    const int hi = lane >> 5;

    // ---- stage small tensors ----
    if (tid < HID) {
        b2s[tid] = b2[tid]; b3s[tid] = b3[tid]; w4s[tid] = w4[tid];
    }
    if (tid < BPB) {
        xs[tid] = x[blockIdx.x * BPB + tid];
        hs[tid] = h[blockIdx.x * BPB + tid];
    }
    if (tid < 56) {
        if (tid < S51) {
            // Faithful port of compute_cc_weights (verified R1-R20)
            const float PI50 = 0.06283185307179586f;  // pi/50
            float acc = 1.0f;
            for (int i = 2; i <= 50; i += 2) {
                int m = (i * tid) % 100;  // exact argument reduction
                acc += (2.0f / (1.0f - (float)(i * i))) * cosf((float)m * PI50);
            }
            float ccw = acc * 0.04f * ((tid == 0 || tid == NSTEP) ? 0.5f : 1.0f);
            fs[tid] = ccw * 0.5f;                               // folds the (x-x0)*0.5 factor
            ts[tid] = (cosf((float)tid * PI50) + 1.0f) * 0.5f;  // (steps+1)/2
        } else {
            ts[tid] = 0.0f;   // masked rows of tile 12 (ss == 51)
        }
    }
    const float b4v = b4[0];
    const float hm = (hi == 0) ? 1.0f : 0.0f;   // zero the k=8..15 half of bf16 frags

    // ---- gather W2^T (PERMUTED K to match L1 D-frag) / W3^T (canonical) ----
    long w2f[8], w3f[8];
    {
        const int irow = mi * 32 + l31;
#pragma unroll
        for (int kc = 0; kc < 8; ++kc) {
            // permuted: hid(e) = (kc>>1)*32 + (kc&1)*16 + 4*hi + (e&3) + 8*(e>>2)
            const int pb = (kc >> 1) * 32 + (kc & 1) * 16 + 4 * hi;
            unsigned lo2 = pk4_fp8(w2[(pb + 0) * HID + irow], w2[(pb + 1) * HID + irow],
                                   w2[(pb + 2) * HID + irow], w2[(pb + 3) * HID + irow]);
            unsigned hi2 = pk4_fp8(w2[(pb + 8) * HID + irow], w2[(pb + 9) * HID + irow],
                                   w2[(pb + 10) * HID + irow], w2[(pb + 11) * HID + irow]);
            w2f[kc] = (long)(((unsigned long long)hi2 << 32) | lo2);
            // canonical: k = kc*16 + hi*8 + e
            const int kb = kc * 16 + hi * 8;
            unsigned lo3 = pk4_fp8(w3[(kb + 0) * HID + irow], w3[(kb + 1) * HID + irow],
                                   w3[(kb + 2) * HID + irow], w3[(kb + 3) * HID + irow]);
            unsigned hi3 = pk4_fp8(w3[(kb + 4) * HID + irow], w3[(kb + 5) * HID + irow],
                                   w3[(kb + 6) * HID + irow], w3[(kb + 7) * HID + irow]);
            w3f[kc] = (long)(((unsigned long long)hi3 << 32) | lo3);
        }
    }
    // ---- W1+b1 bf16 A-frags, one per hidden slice q (k=0:X, k=1:h, k=2:b1) ----
    bf16x8 aw[4];
#pragma unroll
    for (int q = 0; q < 4; ++q) {
        const int j = q * 32 + l31;
        bf16x8 t = {};
        t[0] = (__bf16)(w1[j] * hm);
        t[1] = (__bf16)(w1[HID + j] * hm);
        t[2] = (__bf16)(b1[j] * hm);
        aw[q] = t;
    }
    __syncthreads();

    // per-lane constants: row remap lr = ss*16 + bbl => bbl = row&15 = l31&15
    const float xv = xs[l31 & 15];
    const __bf16 hb = (__bf16)(hs[l31 & 15] * hm);
    float accq = 0.0f;            // wave-0 per-lane quadrature accumulator (bbl = tid&15)

    // XOR-addressing bases (disjoint-bit decomposition, R16-verified)
    const int rb  = l31 * HID + ((l31 & 15) << 3);
    const int rbh = rb ^ (hi << 3);
    const int wbm = (rb + 4 * hi) ^ (mi << 5);

#define PHASE_ARGS A2, posum, b2s, b3s, w4s, fs, ts, accq, w2f, w3f, \
                   aw, xv, hb, hm, b4v, rbh, wbm, tid, l31, hi, mi
    // phase s: L1+L2(tile s) -> A2[s&1]; L3(tile s-1) from A2[(s&1)^1]; consume(s-2)
    phase<0, false, true,  false>(0, PHASE_ARGS);
    phase<1, false, true,  true >(1, PHASE_ARGS);
    for (int it = 0; it < 5; ++it) {
        phase<0, true, true, true>(2 + 2 * it, PHASE_ARGS);
        phase<1, true, true, true>(3 + 2 * it, PHASE_ARGS);
    }
    phase<0, true, true,  true>(12, PHASE_ARGS);
    phase<1, true, false, true>(13, PHASE_ARGS);
#undef PHASE_ARGS

    // final consume: tile 12 (posum[0], written by L4@13), valid rows 768..815
    if (tid < MT) {
        if (tid < RPB - (NTILE - 1) * MT) {   // tid < 48
            float u = posum[0][0][tid] + posum[0][1][tid] + posum[0][2][tid]
                    + posum[0][3][tid] + b4v;
            float dz = u > 0.0f ? u + 1.0f : __expf(u);
            accq += dz * fs[((NTILE - 1) * MT + tid) >> 4];
        }
        // lanes l, l^16, l^32, l^48 share bbl = l&15
        accq += __shfl_xor(accq, 16);
        accq += __shfl_xor(accq, 32);
        if (tid < BPB) out[blockIdx.x * BPB + tid] = hs[tid] + accq * xs[tid];
    }
}

extern "C" void kernel_launch(void* const* d_in, const int* in_sizes, int n_in,
                              void* d_out, int out_size, void* d_ws, size_t ws_size,
                              hipStream_t stream) {
    const float* x  = (const float*)d_in[0];
    const float* h  = (const float*)d_in[1];
    const float* w1 = (const float*)d_in[2];
    const float* b1 = (const float*)d_in[3];
    const float* w2 = (const float*)d_in[4];
    const float* b2 = (const float*)d_in[5];
    const float* w3 = (const float*)d_in[6];
    const float* b3 = (const float*)d_in[7];
    const float* w4 = (const float*)d_in[8];
    const float* b4 = (const float*)d_in[9];
    float* out = (float*)d_out;

    monotonic_fused<<<GRID, BLOCK, 0, stream>>>(x, h, w1, b1, w2, b2, w3, b3, w4, b4, out);
}

// Round 8
// 132.562 us; speedup vs baseline: 1.1939x; 1.1939x over previous
//
#include <hip/hip_runtime.h>
#include <hip/hip_bf16.h>

#define NSTEP 50
#define S51 51
#define HID 128
#define MT 64                  // rows per tile
#define BPB 16                 // batch elems per block (block owns them -> no global atomics)
#define RPB (BPB * S51)        // 816 valid rows per block
#define NTILE 13               // ceil(816/64): 832 rows, 16 masked (1.9% waste)
#define GRID (16384 / BPB)     // 1024 blocks
#define BLOCK 256              // 4 waves; wave mi owns hidden slice [mi*32, mi*32+32)

typedef __attribute__((ext_vector_type(4))) float floatx4;
typedef __attribute__((ext_vector_type(16))) float floatx16;
typedef __attribute__((ext_vector_type(8))) __bf16 bf16x8;

// 4 x f32 -> 4 packed fp8 e4m3 bytes (v_cvt_pk_fp8_f32, gfx950 OCP e4m3fn)
__device__ __forceinline__ unsigned pk4_fp8(float v0, float v1, float v2, float v3) {
    unsigned r = (unsigned)__builtin_amdgcn_cvt_pk_fp8_f32(v0, v1, 0, false);   // bytes 0,1
    r = (unsigned)__builtin_amdgcn_cvt_pk_fp8_f32(v2, v3, (int)r, true);        // bytes 2,3
    return r;
}

// Swizzled fp8 activation layout: row-major 64x128 bytes, rows = 16 chunks of 8B,
// phys_chunk = chunk ^ (row & 15). XOR-base form (R16-verified):
//   base rb  = l31*128 + ((l31&15)<<3)            (disjoint bits -> '+' ok)
//   reads:  addr = (rb ^ (hi<<3)) ^ (kc<<4)  [+4096 for row l31+32]
//   writes: addr = ((rb + 4*hi) ^ (mi<<5)) ^ (g<<3)  [+4096 for row l31+32]

// Register-only C-operand build (address-taken aggregates spill — R7 lesson)
__device__ __forceinline__ floatx16 ld_bias16(const float* bs, int base) {
    const floatx4 t0 = *(const floatx4*)(&bs[base]);
    const floatx4 t1 = *(const floatx4*)(&bs[base + 8]);
    const floatx4 t2 = *(const floatx4*)(&bs[base + 16]);
    const floatx4 t3 = *(const floatx4*)(&bs[base + 24]);
    floatx16 v = {t0[0], t0[1], t0[2], t0[3], t1[0], t1[1], t1[2], t1[3],
                  t2[0], t2[1], t2[2], t2[3], t3[0], t3[1], t3[2], t3[3]};
    return v;
}

// L1 (2->128) on the matrix pipe: one bf16 32x32x16 MFMA per 32x32 block.
// Bias b1 folded into k=2 (aw[2]=b1[j], bx[2]=1*hm), C-in = zero (R17-verified).
// ts[51..55]=0 pads masked rows and the dummy tile-13 build at s=12.
__device__ __forceinline__ void l1_tile(unsigned char* dst, int t,
                                        const float* tsp,
                                        bf16x8 aw, float xv, __bf16 hb, float hm,
                                        int wbm, int l31, int hi, int mi) {
    const int s1 = 4 * t + (l31 >> 4);       // ss for row l31; row l31+32 is +2
    bf16x8 bx0 = {}, bx1 = {};
    bx0[0] = (__bf16)(xv * tsp[s1] * hm);     bx0[1] = hb;  bx0[2] = (__bf16)hm;
    bx1[0] = (__bf16)(xv * tsp[s1 + 2] * hm); bx1[1] = hb;  bx1[2] = (__bf16)hm;
    const floatx16 zz = {};
    floatx16 d0 = __builtin_amdgcn_mfma_f32_32x32x16_bf16(aw, bx0, zz, 0, 0, 0);
    floatx16 d1 = __builtin_amdgcn_mfma_f32_32x32x16_bf16(aw, bx1, zz, 0, 0, 0);
#pragma unroll
    for (int g = 0; g < 4; ++g) {
        unsigned p0 = pk4_fp8(fmaxf(d0[4 * g + 0], 0.0f), fmaxf(d0[4 * g + 1], 0.0f),
                              fmaxf(d0[4 * g + 2], 0.0f), fmaxf(d0[4 * g + 3], 0.0f));
        *(unsigned*)(&dst[wbm ^ (g << 3)]) = p0;
        unsigned p1 = pk4_fp8(fmaxf(d1[4 * g + 0], 0.0f), fmaxf(d1[4 * g + 1], 0.0f),
                              fmaxf(d1[4 * g + 2], 0.0f), fmaxf(d1[4 * g + 3], 0.0f));
        *(unsigned*)(&dst[(wbm ^ (g << 3)) + 4096]) = p1;
    }
}

// R22 = R18 revert (proven 71.4us steady) + L4 on the matrix pipe.
// R21 calibration: Dwall ~ DVALU-busy 1:1 -> VALU is the marginal resource
// (per-SIMD ~49% in R18, MFMA 30%, ~20% latency). L4 was the biggest VALU
// block (130 ops/wave-phase). New path: pack relu(c) to fp8 (24 ops, same
// trusted pack as a2), hi-half interleave via 4x shfl_xor(32)+4 selects (from
// verified c-frag<->B-frag layouts), dot vs broadcast-w4 A-frag (all A rows
// equal -> every D reg holds the dot; no cross-lane reduce). -62 VALU +4 MFMA
// per wave-phase. Precision: 3rd fp8 quantization (L4 input) — absmax may
// rise to ~0.06.
// LEDGER: R16 runtime-parity fuse (spills), R19 ci-hoist@4waves (spills),
// R20 MT=128 (occupancy >> barriers), R21 A1-elim (redundant L1 VALU 4x),
// R9 LDS, R10/R11 occupancy, R13/R14 packed-f32 (not double-rate).
// Spill guard: FETCH <= ~1MB, WRITE ~64KB.
template<int PA, bool CONS, bool L2P, bool L3P, bool L1P>
__device__ __forceinline__ void phase(int s,
        unsigned char (&A1)[2][MT * HID], unsigned char (&A2)[2][MT * HID],
        float (&posum)[2][4][MT],
        const float* b2s, const float* b3s, const long (&w4f)[2],
        const float* fs, const float* ts,
        float& accq, const long (&w2f)[8], const long (&w3f)[8],
        bf16x8 aw, float xv, __bf16 hb, float hm, float b4v,
        int rbh, int wbm, int tid, int l31, int hi, int mi) {
    constexpr int PB = PA ^ 1;
    // ---- consume tile s-2 partials (posum[PA], written phase s-1; lr<RPB
    //      guaranteed for s<=13 here — only the final epilogue needs the mask) ----
    if (CONS) {
        if (tid < MT) {
            int lr = (s - 2) * MT + tid;
            float u = posum[PA][0][tid] + posum[PA][1][tid] + posum[PA][2][tid]
                    + posum[PA][3][tid] + b4v;
            float dz = u > 0.0f ? u + 1.0f : __expf(u);  // elu(u)+1
            accq += dz * fs[lr >> 4];                    // ss = lr>>4
        }
    }
    // ---- L2-MFMA on tile s (read A1[PA]) + fp8 pack -> A2[PA] ----
    if (L2P) {
        const floatx16 ci = ld_bias16(b2s, mi * 32 + 4 * hi);
        long f0 = *(const long*)(&A1[PA][rbh]);
        long f1 = *(const long*)(&A1[PA][rbh + 4096]);
        floatx16 a0 = __builtin_amdgcn_mfma_f32_32x32x16_fp8_fp8(w2f[0], f0, ci, 0, 0, 0);
        floatx16 a1 = __builtin_amdgcn_mfma_f32_32x32x16_fp8_fp8(w2f[0], f1, ci, 0, 0, 0);
#pragma unroll
        for (int kc = 1; kc < 8; ++kc) {
            f0 = *(const long*)(&A1[PA][rbh ^ (kc << 4)]);
            f1 = *(const long*)(&A1[PA][(rbh ^ (kc << 4)) + 4096]);
            a0 = __builtin_amdgcn_mfma_f32_32x32x16_fp8_fp8(w2f[kc], f0, a0, 0, 0, 0);
            a1 = __builtin_amdgcn_mfma_f32_32x32x16_fp8_fp8(w2f[kc], f1, a1, 0, 0, 0);
        }
#pragma unroll
        for (int g = 0; g < 4; ++g) {
            unsigned p0 = pk4_fp8(fmaxf(a0[4 * g + 0], 0.0f), fmaxf(a0[4 * g + 1], 0.0f),
                                  fmaxf(a0[4 * g + 2], 0.0f), fmaxf(a0[4 * g + 3], 0.0f));
            *(unsigned*)(&A2[PA][wbm ^ (g << 3)]) = p0;
            unsigned p1 = pk4_fp8(fmaxf(a1[4 * g + 0], 0.0f), fmaxf(a1[4 * g + 1], 0.0f),
                                  fmaxf(a1[4 * g + 2], 0.0f), fmaxf(a1[4 * g + 3], 0.0f));
            *(unsigned*)(&A2[PA][(wbm ^ (g << 3)) + 4096]) = p1;
        }
    }
    // ---- L3-MFMA on tile s-1 (read A2[PB] — literal-disjoint from pack's A2[PA])
    //      + L4 dot on the MATRIX pipe (R22) -> posum[PB] ----
    if (L3P) {
        const floatx16 ci = ld_bias16(b3s, mi * 32 + 4 * hi);
        long g0 = *(const long*)(&A2[PB][rbh]);
        long g1 = *(const long*)(&A2[PB][rbh + 4096]);
        floatx16 c0 = __builtin_amdgcn_mfma_f32_32x32x16_fp8_fp8(w3f[0], g0, ci, 0, 0, 0);
        floatx16 c1 = __builtin_amdgcn_mfma_f32_32x32x16_fp8_fp8(w3f[0], g1, ci, 0, 0, 0);
#pragma unroll
        for (int kc = 1; kc < 8; ++kc) {
            g0 = *(const long*)(&A2[PB][rbh ^ (kc << 4)]);
            g1 = *(const long*)(&A2[PB][(rbh ^ (kc << 4)) + 4096]);
            c0 = __builtin_amdgcn_mfma_f32_32x32x16_fp8_fp8(w3f[kc], g0, c0, 0, 0, 0);
            c1 = __builtin_amdgcn_mfma_f32_32x32x16_fp8_fp8(w3f[kc], g1, c1, 0, 0, 0);
        }
        const floatx16 zz = {};
        // c0 (tile rows 0..31): pack relu -> fp8, hi-interleave, 2 MFMAs
        {
            unsigned u0 = pk4_fp8(fmaxf(c0[0], 0.0f), fmaxf(c0[1], 0.0f),
                                  fmaxf(c0[2], 0.0f), fmaxf(c0[3], 0.0f));
            unsigned u1 = pk4_fp8(fmaxf(c0[4], 0.0f), fmaxf(c0[5], 0.0f),
                                  fmaxf(c0[6], 0.0f), fmaxf(c0[7], 0.0f));
            unsigned u2 = pk4_fp8(fmaxf(c0[8], 0.0f), fmaxf(c0[9], 0.0f),
                                  fmaxf(c0[10], 0.0f), fmaxf(c0[11], 0.0f));
            unsigned u3 = pk4_fp8(fmaxf(c0[12], 0.0f), fmaxf(c0[13], 0.0f),
                                  fmaxf(c0[14], 0.0f), fmaxf(c0[15], 0.0f));
            unsigned u0p = __shfl_xor(u0, 32), u1p = __shfl_xor(u1, 32);
            unsigned u2p = __shfl_xor(u2, 32), u3p = __shfl_xor(u3, 32);
            // B byte e (lane l31,hi) = relu(c)[k = kc*16 + hi*8 + e][row l31]
            long B0 = hi ? (long)(((unsigned long long)u1 << 32) | u1p)
                         : (long)(((unsigned long long)u0p << 32) | u0);
            long B1 = hi ? (long)(((unsigned long long)u3 << 32) | u3p)
                         : (long)(((unsigned long long)u2p << 32) | u2);
            floatx16 d2 = __builtin_amdgcn_mfma_f32_32x32x16_fp8_fp8(w4f[0], B0, zz, 0, 0, 0);
            d2 = __builtin_amdgcn_mfma_f32_32x32x16_fp8_fp8(w4f[1], B1, d2, 0, 0, 0);
            if (hi == 0) posum[PB][mi][l31] = d2[0];   // all D rows equal = full 32-dot
        }
        // c1 (tile rows 32..63)
        {
            unsigned u0 = pk4_fp8(fmaxf(c1[0], 0.0f), fmaxf(c1[1], 0.0f),
                                  fmaxf(c1[2], 0.0f), fmaxf(c1[3], 0.0f));
            unsigned u1 = pk4_fp8(fmaxf(c1[4], 0.0f), fmaxf(c1[5], 0.0f),
                                  fmaxf(c1[6], 0.0f), fmaxf(c1[7], 0.0f));
            unsigned u2 = pk4_fp8(fmaxf(c1[8], 0.0f), fmaxf(c1[9], 0.0f),
                                  fmaxf(c1[10], 0.0f), fmaxf(c1[11], 0.0f));
            unsigned u3 = pk4_fp8(fmaxf(c1[12], 0.0f), fmaxf(c1[13], 0.0f),
                                  fmaxf(c1[14], 0.0f), fmaxf(c1[15], 0.0f));
            unsigned u0p = __shfl_xor(u0, 32), u1p = __shfl_xor(u1, 32);
            unsigned u2p = __shfl_xor(u2, 32), u3p = __shfl_xor(u3, 32);
            long B0 = hi ? (long)(((unsigned long long)u1 << 32) | u1p)
                         : (long)(((unsigned long long)u0p << 32) | u0);
            long B1 = hi ? (long)(((unsigned long long)u3 << 32) | u3p)
                         : (long)(((unsigned long long)u2p << 32) | u2);
            floatx16 d2 = __builtin_amdgcn_mfma_f32_32x32x16_fp8_fp8(w4f[0], B0, zz, 0, 0, 0);
            d2 = __builtin_amdgcn_mfma_f32_32x32x16_fp8_fp8(w4f[1], B1, d2, 0, 0, 0);
            if (hi == 0) posum[PB][mi][l31 + 32] = d2[0];
        }
    }
    // ---- L1-MFMA for tile s+1 -> A1[PB] (A1[PB] last read phase s-1) ----
    if (L1P) {
        l1_tile(A1[PB], s + 1, ts, aw, xv, hb, hm, wbm, l31, hi, mi);
    }
    __syncthreads();
}

__launch_bounds__(BLOCK, 4)
__global__ void monotonic_fused(const float* __restrict__ x, const float* __restrict__ h,
                                const float* __restrict__ w1, const float* __restrict__ b1,
                                const float* __restrict__ w2, const float* __restrict__ b2,
                                const float* __restrict__ w3, const float* __restrict__ b3,
                                const float* __restrict__ w4, const float* __restrict__ b4,
                                float* __restrict__ out) {
    __shared__ __align__(16) unsigned char A1[2][MT * HID];  // a1 fp8, 2 x 8 KB
    __shared__ __align__(16) unsigned char A2[2][MT * HID];  // a2 fp8, 2 x 8 KB
    __shared__ float b2s[HID], b3s[HID], w4s[HID];
    __shared__ float fs[S51], ts[56];                        // ts[51..55]=0 pad
    __shared__ float xs[BPB], hs[BPB];
    __shared__ float posum[2][4][MT];                        // parity x mi x row

    const int tid = threadIdx.x;
    const int lane = tid & 63;
    const int mi = tid >> 6;      // wave 0..3 = hidden 32-slice
    const int l31 = lane & 31;
    const int hi = lane >> 5;

    // ---- stage small tensors ----
    if (tid < HID) {
        b2s[tid] = b2[tid]; b3s[tid] = b3[tid]; w4s[tid] = w4[tid];
    }
    if (tid < BPB) {
        xs[tid] = x[blockIdx.x * BPB + tid];
        hs[tid] = h[blockIdx.x * BPB + tid];
    }
    if (tid < 56) {
        if (tid < S51) {
            // Faithful port of compute_cc_weights (verified R1-R21)
            const float PI50 = 0.06283185307179586f;  // pi/50
            float acc = 1.0f;
            for (int i = 2; i <= 50; i += 2) {
                int m = (i * tid) % 100;  // exact argument reduction
                acc += (2.0f / (1.0f - (float)(i * i))) * cosf((float)m * PI50);
            }
            float ccw = acc * 0.04f * ((tid == 0 || tid == NSTEP) ? 0.5f : 1.0f);
            fs[tid] = ccw * 0.5f;                               // folds the (x-x0)*0.5 factor
            ts[tid] = (cosf((float)tid * PI50) + 1.0f) * 0.5f;  // (steps+1)/2
        } else {
            ts[tid] = 0.0f;   // masked rows (ss=51) and dummy tile-13 build (52..55)
        }
    }
    const float b4v = b4[0];
    const float hm = (hi == 0) ? 1.0f : 0.0f;   // zero the k=8..15 half of bf16 frags

    // ---- gather W2^T / W3^T A-operand fp8 fragments (coalesced over l31) ----
    long w2f[8], w3f[8];
    {
        const int irow = mi * 32 + l31;
#pragma unroll
        for (int kc = 0; kc < 8; ++kc) {
            const int kb = kc * 16 + hi * 8;
            unsigned lo2 = pk4_fp8(w2[(kb + 0) * HID + irow], w2[(kb + 1) * HID + irow],
                                   w2[(kb + 2) * HID + irow], w2[(kb + 3) * HID + irow]);
            unsigned hi2 = pk4_fp8(w2[(kb + 4) * HID + irow], w2[(kb + 5) * HID + irow],
                                   w2[(kb + 6) * HID + irow], w2[(kb + 7) * HID + irow]);
            w2f[kc] = (long)(((unsigned long long)hi2 << 32) | lo2);
            unsigned lo3 = pk4_fp8(w3[(kb + 0) * HID + irow], w3[(kb + 1) * HID + irow],
                                   w3[(kb + 2) * HID + irow], w3[(kb + 3) * HID + irow]);
            unsigned hi3 = pk4_fp8(w3[(kb + 4) * HID + irow], w3[(kb + 5) * HID + irow],
                                   w3[(kb + 6) * HID + irow], w3[(kb + 7) * HID + irow]);
            w3f[kc] = (long)(((unsigned long long)hi3 << 32) | lo3);
        }
    }
    // ---- W1+b1 bf16 A-frag (once): k=0 -> w1[0][j], k=1 -> w1[1][j], k=2 -> b1[j] ----
    bf16x8 aw = {};
    {
        const int j = mi * 32 + l31;
        aw[0] = (__bf16)(w1[j] * hm);
        aw[1] = (__bf16)(w1[HID + j] * hm);
        aw[2] = (__bf16)(b1[j] * hm);
    }
    __syncthreads();

    // ---- w4 broadcast A-frags (R22): A[i][k] = w4[mi*32 + kc*16 + hi*8 + e],
    //      identical for all rows i -> every D reg holds the full row-dot ----
    long w4f[2];
    {
        const int base = mi * 32 + hi * 8;
        unsigned lo0 = pk4_fp8(w4s[base + 0], w4s[base + 1], w4s[base + 2], w4s[base + 3]);
        unsigned hi0 = pk4_fp8(w4s[base + 4], w4s[base + 5], w4s[base + 6], w4s[base + 7]);
        w4f[0] = (long)(((unsigned long long)hi0 << 32) | lo0);
        unsigned lo1 = pk4_fp8(w4s[base + 16], w4s[base + 17], w4s[base + 18], w4s[base + 19]);
        unsigned hi1 = pk4_fp8(w4s[base + 20], w4s[base + 21], w4s[base + 22], w4s[base + 23]);
        w4f[1] = (long)(((unsigned long long)hi1 << 32) | lo1);
    }

    // per-lane constants: row remap lr = ss*16 + bbl  =>  bbl = r&15 fixed per lane
    const float xv = xs[l31 & 15];
    const __bf16 hb = (__bf16)(hs[l31 & 15] * hm);
    float accq = 0.0f;            // wave-0 per-lane quadrature accumulator (bbl = tid&15)

    // XOR-addressing bases (disjoint-bit decomposition of sw8, R16-verified)
    const int rb  = l31 * HID + ((l31 & 15) << 3);
    const int rbh = rb ^ (hi << 3);
    const int wbm = (rb + 4 * hi) ^ (mi << 5);

    // ---- L1 for tile 0 -> A1[0] ----
    l1_tile(A1[0], 0, ts, aw, xv, hb, hm, wbm, l31, hi, mi);
    __syncthreads();

#define PHASE_ARGS A1, A2, posum, b2s, b3s, w4f, fs, ts, accq, w2f, w3f, \
                   aw, xv, hb, hm, b4v, rbh, wbm, tid, l31, hi, mi
    // edge phases 0,1; steady fused 2..12; edge 13 (parity literal throughout)
    phase<0, false, true, false, true >(0, PHASE_ARGS);
    phase<1, false, true, true,  true >(1, PHASE_ARGS);
    for (int it = 0; it < 5; ++it) {
        phase<0, true, true, true, true>(2 + 2 * it, PHASE_ARGS);
        phase<1, true, true, true, true>(3 + 2 * it, PHASE_ARGS);
    }
    phase<0, true, true,  true, true >(12, PHASE_ARGS);
    phase<1, true, false, true, false>(13, PHASE_ARGS);
#undef PHASE_ARGS

    // final consume: tile 12 (posum[0], written by L4@13), masked rows 816..831;
    // then cross-lane reduce (lanes l, l^16, l^32, l^48 share bbl = l&15).
    if (tid < MT) {
        int lr = (NTILE - 1) * MT + tid;
        if (lr < RPB) {
            float u = posum[0][0][tid] + posum[0][1][tid] + posum[0][2][tid]
                    + posum[0][3][tid] + b4v;
            float dz = u > 0.0f ? u + 1.0f : __expf(u);
            accq += dz * fs[lr >> 4];
        }
        accq += __shfl_xor(accq, 16);
        accq += __shfl_xor(accq, 32);
        if (tid < BPB) out[blockIdx.x * BPB + tid] = hs[tid] + accq * xs[tid];
    }
}

extern "C" void kernel_launch(void* const* d_in, const int* in_sizes, int n_in,
                              void* d_out, int out_size, void* d_ws, size_t ws_size,
                              hipStream_t stream) {
    const float* x  = (const float*)d_in[0];
    const float* h  = (const float*)d_in[1];
    const float* w1 = (const float*)d_in[2];
    const float* b1 = (const float*)d_in[3];
    const float* w2 = (const float*)d_in[4];
    const float* b2 = (const float*)d_in[5];
    const float* w3 = (const float*)d_in[6];
    const float* b3 = (const float*)d_in[7];
    const float* w4 = (const float*)d_in[8];
    const float* b4 = (const float*)d_in[9];
    float* out = (float*)d_out;

    monotonic_fused<<<GRID, BLOCK, 0, stream>>>(x, h, w1, b1, w2, b2, w3, b3, w4, b4, out);
}

// Round 9
// 130.014 us; speedup vs baseline: 1.2174x; 1.0196x over previous
//
#include <hip/hip_runtime.h>
#include <hip/hip_bf16.h>

#define NSTEP 50
#define S51 51
#define HID 128
#define MT 64                  // rows per tile
#define BPB 16                 // batch elems per block (block owns them -> no global atomics)
#define RPB (BPB * S51)        // 816 valid rows per block
#define NTILE 13               // ceil(816/64): 832 rows, 16 masked (1.9% waste)
#define GRID (16384 / BPB)     // 1024 blocks
#define BLOCK 256              // 4 waves; wave mi owns hidden slice [mi*32, mi*32+32)

typedef __attribute__((ext_vector_type(2))) int intx2;
typedef __attribute__((ext_vector_type(8))) int intx8;
typedef __attribute__((ext_vector_type(4))) float floatx4;
typedef __attribute__((ext_vector_type(16))) float floatx16;
typedef __attribute__((ext_vector_type(8))) __bf16 bf16x8;

// 4 x f32 -> 4 packed fp8 e4m3 bytes (v_cvt_pk_fp8_f32, gfx950 OCP e4m3fn)
__device__ __forceinline__ unsigned pk4_fp8(float v0, float v1, float v2, float v3) {
    unsigned r = (unsigned)__builtin_amdgcn_cvt_pk_fp8_f32(v0, v1, 0, false);   // bytes 0,1
    r = (unsigned)__builtin_amdgcn_cvt_pk_fp8_f32(v2, v3, (int)r, true);        // bytes 2,3
    return r;
}

// MX-scaled K=64 fp8 MFMA with unit scales (E8M0 0x7f = 2^0): bit-identical
// fp8*fp8+f32 arithmetic at 2.14x rate (m59: 4686 vs 2190 TF). fmt 0 = e4m3.
__device__ __forceinline__ floatx16 mx_mfma(intx8 a, intx8 b, floatx16 c) {
    return __builtin_amdgcn_mfma_scale_f32_32x32x64_f8f6f4(
        a, b, c, 0, 0, 0, 0x7f7f7f7f, 0, 0x7f7f7f7f);
}

// Swizzled fp8 activation layout: row-major 64x128 bytes, rows = 16 chunks of 8B,
// phys_chunk = chunk ^ (row & 15). XOR-base form (R16-verified). K=64 frag (R23):
// logical chunk c = kq*8 + hi*4 + j (j=0..3) -> addr = rbase ^ (kq<<6) ^ (j<<3)
// with rbase = l31*128 + ((hi<<5) ^ ((l31&15)<<3))  [+4096 for row l31+32].
// Writes unchanged: addr = wbm ^ (g<<3)  [+4096], wbm = (rb+4*hi) ^ (mi<<5).

// Register-only C-operand build (address-taken aggregates spill — R7 lesson)
__device__ __forceinline__ floatx16 ld_bias16(const float* bs, int base) {
    const floatx4 t0 = *(const floatx4*)(&bs[base]);
    const floatx4 t1 = *(const floatx4*)(&bs[base + 8]);
    const floatx4 t2 = *(const floatx4*)(&bs[base + 16]);
    const floatx4 t3 = *(const floatx4*)(&bs[base + 24]);
    floatx16 v = {t0[0], t0[1], t0[2], t0[3], t1[0], t1[1], t1[2], t1[3],
                  t2[0], t2[1], t2[2], t2[3], t3[0], t3[1], t3[2], t3[3]};
    return v;
}

// 32-byte K=64 B-fragment from swizzled LDS: 4 x ds_read_b64 at XOR offsets,
// assembled in logical order (loads land in the v8 regs directly — no moves).
__device__ __forceinline__ intx8 ld_frag(const unsigned char* p, int addr) {
    intx2 q0 = *(const intx2*)(p + (addr ^ 0));
    intx2 q1 = *(const intx2*)(p + (addr ^ 8));
    intx2 q2 = *(const intx2*)(p + (addr ^ 16));
    intx2 q3 = *(const intx2*)(p + (addr ^ 24));
    intx8 v;
    v[0] = q0[0]; v[1] = q0[1];
    v[2] = q1[0]; v[3] = q1[1];
    v[4] = q2[0]; v[5] = q2[1];
    v[6] = q3[0]; v[7] = q3[1];
    return v;
}

// L1 (2->128) on the matrix pipe: one bf16 32x32x16 MFMA per 32x32 block.
// Bias b1 folded into k=2 (aw[2]=b1[j], bx[2]=1*hm), C-in = zero (R17-verified).
// ts[51..55]=0 pads masked rows and the dummy tile-13 build at s=12.
__device__ __forceinline__ void l1_tile(unsigned char* dst, int t,
                                        const float* tsp,
                                        bf16x8 aw, float xv, __bf16 hb, float hm,
                                        int wbm, int l31, int hi, int mi) {
    const int s1 = 4 * t + (l31 >> 4);       // ss for row l31; row l31+32 is +2
    bf16x8 bx0 = {}, bx1 = {};
    bx0[0] = (__bf16)(xv * tsp[s1] * hm);     bx0[1] = hb;  bx0[2] = (__bf16)hm;
    bx1[0] = (__bf16)(xv * tsp[s1 + 2] * hm); bx1[1] = hb;  bx1[2] = (__bf16)hm;
    const floatx16 zz = {};
    floatx16 d0 = __builtin_amdgcn_mfma_f32_32x32x16_bf16(aw, bx0, zz, 0, 0, 0);
    floatx16 d1 = __builtin_amdgcn_mfma_f32_32x32x16_bf16(aw, bx1, zz, 0, 0, 0);
#pragma unroll
    for (int g = 0; g < 4; ++g) {
        unsigned p0 = pk4_fp8(fmaxf(d0[4 * g + 0], 0.0f), fmaxf(d0[4 * g + 1], 0.0f),
                              fmaxf(d0[4 * g + 2], 0.0f), fmaxf(d0[4 * g + 3], 0.0f));
        *(unsigned*)(&dst[wbm ^ (g << 3)]) = p0;
        unsigned p1 = pk4_fp8(fmaxf(d1[4 * g + 0], 0.0f), fmaxf(d1[4 * g + 1], 0.0f),
                              fmaxf(d1[4 * g + 2], 0.0f), fmaxf(d1[4 * g + 3], 0.0f));
        *(unsigned*)(&dst[(wbm ^ (g << 3)) + 4096]) = p1;
    }
}

// R23 = R18 structure (proven 71.4us steady) with L2/L3 on the MX-scaled
// K=64 fp8 MFMA (unit scales): 32 x mfma_32x32x16 (8 cyc) -> 8 x
// mfma_scale_32x32x64 (~17 cyc) = -46% matrix-pipe time, -24 issue slots.
// Frag layout: verified K=16 mapping (byte e <-> k=hi*8+e) extended to K=64
// as k = hi*32+e for A and B. Unit scale => bit-identical arithmetic.
// R22 post-mortem: L4-on-MFMA neutral — pack+shfl build cost ate the VALU
// saving (shfl lands on DS pipe). Reverted; L4 back on VALU.
// LEDGER: R16 runtime-parity fuse (spills), R19 ci-hoist@4waves (spills),
// R20 MT=128 (occupancy >> barriers), R21 A1-elim (redundant L1 VALU),
// R22 L4-MFMA (neutral), R9 LDS, R10/R11 occupancy, R13/R14 packed-f32.
// Spill guard: FETCH <= ~1MB, WRITE ~64KB. absmax guard: must stay 0.03125
// (if garbage -> K=64 frag layout wrong -> revert).
template<int PA, bool CONS, bool L2P, bool L3P, bool L1P>
__device__ __forceinline__ void phase(int s,
        unsigned char (&A1)[2][MT * HID], unsigned char (&A2)[2][MT * HID],
        float (&posum)[2][4][MT],
        const float* b2s, const float* b3s, const float* w4s,
        const float* fs, const float* ts,
        float& accq, const intx8 (&w2q)[2], const intx8 (&w3q)[2],
        bf16x8 aw, float xv, __bf16 hb, float hm, float b4v,
        int rbase, int wbm, int tid, int l31, int hi, int mi) {
    constexpr int PB = PA ^ 1;
    // ---- consume tile s-2 partials (posum[PA], written phase s-1; lr<RPB
    //      guaranteed for s<=13 here — only the final epilogue needs the mask) ----
    if (CONS) {
        if (tid < MT) {
            int lr = (s - 2) * MT + tid;
            float u = posum[PA][0][tid] + posum[PA][1][tid] + posum[PA][2][tid]
                    + posum[PA][3][tid] + b4v;
            float dz = u > 0.0f ? u + 1.0f : __expf(u);  // elu(u)+1
            accq += dz * fs[lr >> 4];                    // ss = lr>>4
        }
    }
    // ---- L2 on tile s (read A1[PA]): 2 row-halves x 2 K-blocks, 4 MX MFMAs;
    //      then fp8 pack -> A2[PA] ----
    if (L2P) {
        const floatx16 ci = ld_bias16(b2s, mi * 32 + 4 * hi);
        intx8 b00 = ld_frag(&A1[PA][0], rbase);
        floatx16 a0 = mx_mfma(w2q[0], b00, ci);
        intx8 b01 = ld_frag(&A1[PA][0], rbase ^ 64);
        a0 = mx_mfma(w2q[1], b01, a0);
        intx8 b10 = ld_frag(&A1[PA][0], rbase + 4096);
        floatx16 a1 = mx_mfma(w2q[0], b10, ci);
        intx8 b11 = ld_frag(&A1[PA][0], (rbase ^ 64) + 4096);
        a1 = mx_mfma(w2q[1], b11, a1);
#pragma unroll
        for (int g = 0; g < 4; ++g) {
            unsigned p0 = pk4_fp8(fmaxf(a0[4 * g + 0], 0.0f), fmaxf(a0[4 * g + 1], 0.0f),
                                  fmaxf(a0[4 * g + 2], 0.0f), fmaxf(a0[4 * g + 3], 0.0f));
            *(unsigned*)(&A2[PA][wbm ^ (g << 3)]) = p0;
            unsigned p1 = pk4_fp8(fmaxf(a1[4 * g + 0], 0.0f), fmaxf(a1[4 * g + 1], 0.0f),
                                  fmaxf(a1[4 * g + 2], 0.0f), fmaxf(a1[4 * g + 3], 0.0f));
            *(unsigned*)(&A2[PA][(wbm ^ (g << 3)) + 4096]) = p1;
        }
    }
    // ---- L3 on tile s-1 (read A2[PB] — literal-disjoint from pack's A2[PA]):
    //      4 MX MFMAs + fused L4 (VALU, R18-proven) -> posum[PB] ----
    if (L3P) {
        const floatx16 ci = ld_bias16(b3s, mi * 32 + 4 * hi);
        intx8 g00 = ld_frag(&A2[PB][0], rbase);
        floatx16 c0 = mx_mfma(w3q[0], g00, ci);
        intx8 g01 = ld_frag(&A2[PB][0], rbase ^ 64);
        c0 = mx_mfma(w3q[1], g01, c0);
        intx8 g10 = ld_frag(&A2[PB][0], rbase + 4096);
        floatx16 c1 = mx_mfma(w3q[0], g10, ci);
        intx8 g11 = ld_frag(&A2[PB][0], (rbase ^ 64) + 4096);
        c1 = mx_mfma(w3q[1], g11, c1);
        float p0 = 0.0f, p1 = 0.0f;
#pragma unroll
        for (int g = 0; g < 4; ++g) {
            const floatx4 w4v = *(const floatx4*)(&w4s[mi * 32 + 8 * g + 4 * hi]);
#pragma unroll
            for (int rr = 0; rr < 4; ++rr) {
                p0 = fmaf(fmaxf(c0[4 * g + rr], 0.0f), w4v[rr], p0);
                p1 = fmaf(fmaxf(c1[4 * g + rr], 0.0f), w4v[rr], p1);
            }
        }
        p0 += __shfl_xor(p0, 32);
        p1 += __shfl_xor(p1, 32);
        if (hi == 0) {
            posum[PB][mi][l31] = p0;
            posum[PB][mi][l31 + 32] = p1;
        }
    }
    // ---- L1-MFMA for tile s+1 -> A1[PB] (A1[PB] last read phase s-1) ----
    if (L1P) {
        l1_tile(A1[PB], s + 1, ts, aw, xv, hb, hm, wbm, l31, hi, mi);
    }
    __syncthreads();
}

__launch_bounds__(BLOCK, 4)
__global__ void monotonic_fused(const float* __restrict__ x, const float* __restrict__ h,
                                const float* __restrict__ w1, const float* __restrict__ b1,
                                const float* __restrict__ w2, const float* __restrict__ b2,
                                const float* __restrict__ w3, const float* __restrict__ b3,
                                const float* __restrict__ w4, const float* __restrict__ b4,
                                float* __restrict__ out) {
    __shared__ __align__(16) unsigned char A1[2][MT * HID];  // a1 fp8, 2 x 8 KB
    __shared__ __align__(16) unsigned char A2[2][MT * HID];  // a2 fp8, 2 x 8 KB
    __shared__ float b2s[HID], b3s[HID], w4s[HID];
    __shared__ float fs[S51], ts[56];                        // ts[51..55]=0 pad
    __shared__ float xs[BPB], hs[BPB];
    __shared__ float posum[2][4][MT];                        // parity x mi x row

    const int tid = threadIdx.x;
    const int lane = tid & 63;
    const int mi = tid >> 6;      // wave 0..3 = hidden 32-slice
    const int l31 = lane & 31;
    const int hi = lane >> 5;

    // ---- stage small tensors ----
    if (tid < HID) {
        b2s[tid] = b2[tid]; b3s[tid] = b3[tid]; w4s[tid] = w4[tid];
    }
    if (tid < BPB) {
        xs[tid] = x[blockIdx.x * BPB + tid];
        hs[tid] = h[blockIdx.x * BPB + tid];
    }
    if (tid < 56) {
        if (tid < S51) {
            // Faithful port of compute_cc_weights (verified R1-R22)
            const float PI50 = 0.06283185307179586f;  // pi/50
            float acc = 1.0f;
            for (int i = 2; i <= 50; i += 2) {
                int m = (i * tid) % 100;  // exact argument reduction
                acc += (2.0f / (1.0f - (float)(i * i))) * cosf((float)m * PI50);
            }
            float ccw = acc * 0.04f * ((tid == 0 || tid == NSTEP) ? 0.5f : 1.0f);
            fs[tid] = ccw * 0.5f;                               // folds the (x-x0)*0.5 factor
            ts[tid] = (cosf((float)tid * PI50) + 1.0f) * 0.5f;  // (steps+1)/2
        } else {
            ts[tid] = 0.0f;   // masked rows (ss=51) and dummy tile-13 build (52..55)
        }
    }
    const float b4v = b4[0];
    const float hm = (hi == 0) ? 1.0f : 0.0f;   // zero the k=8..15 half of bf16 frags

    // ---- gather W2^T / W3^T K=64 A-fragments: reg j byte b of block kq holds
    //      W[k = kq*64 + hi*32 + 4j + b][hidden = mi*32 + l31] (coalesced l31) ----
    intx8 w2q[2], w3q[2];
    {
        const int irow = mi * 32 + l31;
#pragma unroll
        for (int kq = 0; kq < 2; ++kq) {
            intx8 t2, t3;
#pragma unroll
            for (int j = 0; j < 8; ++j) {
                const int k0 = kq * 64 + hi * 32 + 4 * j;
                t2[j] = (int)pk4_fp8(w2[(k0 + 0) * HID + irow], w2[(k0 + 1) * HID + irow],
                                     w2[(k0 + 2) * HID + irow], w2[(k0 + 3) * HID + irow]);
                t3[j] = (int)pk4_fp8(w3[(k0 + 0) * HID + irow], w3[(k0 + 1) * HID + irow],
                                     w3[(k0 + 2) * HID + irow], w3[(k0 + 3) * HID + irow]);
            }
            w2q[kq] = t2; w3q[kq] = t3;
        }
    }
    // ---- W1+b1 bf16 A-frag (once): k=0 -> w1[0][j], k=1 -> w1[1][j], k=2 -> b1[j] ----
    bf16x8 aw = {};
    {
        const int j = mi * 32 + l31;
        aw[0] = (__bf16)(w1[j] * hm);
        aw[1] = (__bf16)(w1[HID + j] * hm);
        aw[2] = (__bf16)(b1[j] * hm);
    }
    __syncthreads();

    // per-lane constants: row remap lr = ss*16 + bbl  =>  bbl = r&15 fixed per lane
    const float xv = xs[l31 & 15];
    const __bf16 hb = (__bf16)(hs[l31 & 15] * hm);
    float accq = 0.0f;            // wave-0 per-lane quadrature accumulator (bbl = tid&15)

    // XOR-addressing bases (disjoint-bit decomposition, R16-verified; K=64 read
    // base per the R23 derivation in the layout comment above)
    const int rb    = l31 * HID + ((l31 & 15) << 3);
    const int rbase = l31 * HID + ((hi << 5) ^ ((l31 & 15) << 3));
    const int wbm   = (rb + 4 * hi) ^ (mi << 5);

    // ---- L1 for tile 0 -> A1[0] ----
    l1_tile(A1[0], 0, ts, aw, xv, hb, hm, wbm, l31, hi, mi);
    __syncthreads();

#define PHASE_ARGS A1, A2, posum, b2s, b3s, w4s, fs, ts, accq, w2q, w3q, \
                   aw, xv, hb, hm, b4v, rbase, wbm, tid, l31, hi, mi
    // edge phases 0,1; steady fused 2..12; edge 13 (parity literal throughout)
    phase<0, false, true, false, true >(0, PHASE_ARGS);
    phase<1, false, true, true,  true >(1, PHASE_ARGS);
    for (int it = 0; it < 5; ++it) {
        phase<0, true, true, true, true>(2 + 2 * it, PHASE_ARGS);
        phase<1, true, true, true, true>(3 + 2 * it, PHASE_ARGS);
    }
    phase<0, true, true,  true, true >(12, PHASE_ARGS);
    phase<1, true, false, true, false>(13, PHASE_ARGS);
#undef PHASE_ARGS

    // final consume: tile 12 (posum[0], written by L4@13), masked rows 816..831;
    // then cross-lane reduce (lanes l, l^16, l^32, l^48 share bbl = l&15).
    if (tid < MT) {
        int lr = (NTILE - 1) * MT + tid;
        if (lr < RPB) {
            float u = posum[0][0][tid] + posum[0][1][tid] + posum[0][2][tid]
                    + posum[0][3][tid] + b4v;
            float dz = u > 0.0f ? u + 1.0f : __expf(u);
            accq += dz * fs[lr >> 4];
        }
        accq += __shfl_xor(accq, 16);
        accq += __shfl_xor(accq, 32);
        if (tid < BPB) out[blockIdx.x * BPB + tid] = hs[tid] + accq * xs[tid];
    }
}

extern "C" void kernel_launch(void* const* d_in, const int* in_sizes, int n_in,
                              void* d_out, int out_size, void* d_ws, size_t ws_size,
                              hipStream_t stream) {
    const float* x  = (const float*)d_in[0];
    const float* h  = (const float*)d_in[1];
    const float* w1 = (const float*)d_in[2];
    const float* b1 = (const float*)d_in[3];
    const float* w2 = (const float*)d_in[4];
    const float* b2 = (const float*)d_in[5];
    const float* w3 = (const float*)d_in[6];
    const float* b3 = (const float*)d_in[7];
    const float* w4 = (const float*)d_in[8];
    const float* b4 = (const float*)d_in[9];
    float* out = (float*)d_out;

    monotonic_fused<<<GRID, BLOCK, 0, stream>>>(x, h, w1, b1, w2, b2, w3, b3, w4, b4, out);
}